// Round 8
// baseline (3117.244 us; speedup 1.0000x reference)
//
#include <hip/hip_runtime.h>
#include <hip/hip_bf16.h>

typedef __hip_bfloat16 bf16;
typedef __attribute__((ext_vector_type(8))) short short8;
typedef __attribute__((ext_vector_type(4))) float f32x4;
#define DEV __device__ __forceinline__

// Adaptive input load: flag==1 -> fp32 data, flag==0 -> bf16 data.
DEV float ldin(const void* p, long long i, int f) {
  return f ? ((const float*)p)[i]
           : __uint_as_float(((unsigned)((const unsigned short*)p)[i]) << 16);
}
DEV unsigned short f2bf(float x) {  // RNE f32->bf16
  unsigned u = __float_as_uint(x);
  return (unsigned short)((u + 0x7FFFu + ((u >> 16) & 1u)) >> 16);
}
DEV float bf2f(unsigned short h) { return __uint_as_float((unsigned)h << 16); }

// -------------------------------------------- fused detect + NMS + top-k sort
DEV void mp5f(const float* in, float* tmp, float* out, int t) {
  for (int i = t; i < 5000; i += 1024) {
    int y = i / 100, x = i % 100;
    int x0 = x - 2 < 0 ? 0 : x - 2, x1 = x + 2 > 99 ? 99 : x + 2;
    float m = -INFINITY;
    for (int xx = x0; xx <= x1; xx++) m = fmaxf(m, in[y * 100 + xx]);
    tmp[i] = m;
  }
  __syncthreads();
  for (int i = t; i < 5000; i += 1024) {
    int y = i / 100, x = i % 100;
    int y0 = y - 2 < 0 ? 0 : y - 2, y1 = y + 2 > 49 ? 49 : y + 2;
    float m = -INFINITY;
    for (int yy = y0; yy <= y1; yy++) m = fmaxf(m, tmp[yy * 100 + x]);
    out[i] = m;
  }
  __syncthreads();
}

__global__ __launch_bounds__(1024) void k_front(
    const void* __restrict__ scores, const void* __restrict__ dist,
    int* __restrict__ flagO, int* __restrict__ idxO, float* __restrict__ valsO,
    float* __restrict__ maskO, int* __restrict__ nvp) {
  extern __shared__ float lds[];
  float* S = lds;                 // 5000
  float* MK = lds + 5000;         // 5000
  float* Z = lds + 10000;         // 20000 scratch (T,P,SP,SS / keys)
  float* T = Z;
  float* P = Z + 5000;
  float* SP = Z + 10000;
  float* SS = Z + 15000;
  unsigned long long* keys = (unsigned long long*)(lds + 10000);  // 8192 u64
  __shared__ int bad, cnt;
  const int bb = blockIdx.x, t = threadIdx.x;
  if (t == 0) { bad = 0; cnt = 0; }
  __syncthreads();
  {
    int c = 0;
    const unsigned short* p = (const unsigned short*)dist;
    for (int i = t; i < 65536; i += 1024) {
      unsigned e = (p[i] >> 7) & 0xFF;
      if (e >= 0x86) c++;
    }
    atomicAdd(&bad, c);
  }
  __syncthreads();
  const int f = (bad > 100) ? 1 : 0;
  if (bb == 0 && t == 0) *flagO = f;
  for (int i = t; i < 5000; i += 1024) S[i] = ldin(scores, bb * 5000 + i, f);
  __syncthreads();
  mp5f(S, T, P, t);
  for (int i = t; i < 5000; i += 1024) MK[i] = (S[i] == P[i]) ? 1.f : 0.f;
  __syncthreads();
  for (int r = 0; r < 2; r++) {
    mp5f(MK, T, P, t);
    for (int i = t; i < 5000; i += 1024) {
      SP[i] = (P[i] > 0.f) ? 1.f : 0.f;
      SS[i] = (SP[i] != 0.f) ? 0.f : S[i];
    }
    __syncthreads();
    mp5f(SS, T, P, t);
    for (int i = t; i < 5000; i += 1024)
      if (MK[i] == 0.f) MK[i] = ((SS[i] == P[i]) && (SP[i] == 0.f)) ? 1.f : 0.f;
    __syncthreads();
  }
  for (int i = t; i < 8192; i += 1024) {
    unsigned long long kk;
    if (i < 5000) {
      float v = (MK[i] != 0.f) ? S[i] : 0.f;
      unsigned vb = __float_as_uint(v);
      kk = ((unsigned long long)vb << 32) | (unsigned)(0xFFFFFFFFu - (unsigned)i);
    } else {
      kk = 0ull;
    }
    keys[i] = ~kk;
  }
  __syncthreads();
  for (int k = 2; k <= 8192; k <<= 1) {
    for (int j = k >> 1; j > 0; j >>= 1) {
      for (int i = t; i < 8192; i += 1024) {
        int ixj = i ^ j;
        if (ixj > i) {
          unsigned long long a = keys[i], b = keys[ixj];
          bool up = ((i & k) == 0);
          if (up ? (a > b) : (a < b)) { keys[i] = b; keys[ixj] = a; }
        }
      }
      __syncthreads();
    }
  }
  {
    unsigned long long kk = ~keys[t];
    unsigned idx = 0xFFFFFFFFu - (unsigned)(kk & 0xFFFFFFFFu);
    float v = __uint_as_float((unsigned)(kk >> 32));
    idxO[bb * 1024 + t] = (int)idx;
    valsO[bb * 1024 + t] = v;
    bool valid = (v > 0.015f);
    maskO[bb * 1024 + t] = valid ? 1.f : 0.f;
    unsigned long long bal = __ballot(valid);
    if ((t & 63) == 0) atomicAdd(&cnt, (int)__popcll(bal));
  }
  __syncthreads();
  if (t == 0) nvp[bb] = cnt;
}

// -------------------------------- weight prep: split all weights to hi/lo bf16
// Segments (elem offsets): W0pad 0 | We1 65536 | Wqkv(row-perm) 131072 |
// Wm(col-perm) 917504 | W1 1179648 | W2 2228224 | Wf 2752512 | end 2818048
__global__ void k_prep(const void* __restrict__ W0, const void* __restrict__ W1e,
                       const void* __restrict__ Wqkv, const void* __restrict__ Wm,
                       const void* __restrict__ W1g, const void* __restrict__ W2g,
                       const void* __restrict__ Wf, unsigned short* __restrict__ WH,
                       unsigned short* __restrict__ WL, const int* __restrict__ flagp) {
  const int f = *flagp;
  long long g = (long long)blockIdx.x * 256 + threadIdx.x;
  float val;
  if (g < 65536) {
    int r = (int)(g >> 8), c = (int)(g & 255);
    val = (c < 235) ? ldin(W0, (long long)r * 235 + c, f) : 0.f;
  } else if (g < 131072) {
    val = ldin(W1e, g - 65536, f);
  } else if (g < 917504) {
    long long L = g - 131072;
    int R = (int)(L >> 8), k = (int)(L & 255);
    int l = R / 768, rp = R % 768;
    int qkv = rp >> 8, cp = rp & 255, h = cp >> 6, d = cp & 63;
    val = ldin(Wqkv, ((long long)((l * 3 + qkv) * 256 + d * 4 + h)) * 256 + k, f);
  } else if (g < 1179648) {
    long long L = g - 917504;
    int n = (int)(L >> 8), kp = (int)(L & 255);
    int k = (kp & 63) * 4 + (kp >> 6);
    val = ldin(Wm, (long long)n * 256 + k, f);
  } else if (g < 2228224) {
    val = ldin(W1g, g - 1179648, f);
  } else if (g < 2752512) {
    val = ldin(W2g, g - 2228224, f);
  } else {
    val = ldin(Wf, g - 2752512, f);
  }
  unsigned short h_ = f2bf(val);
  WH[g] = h_;
  WL[g] = f2bf(val - bf2f(h_));
}

// --------------------------------------------------------- embedding (planes)
__global__ void k_emb(const int* __restrict__ idxO, const float* __restrict__ valsO,
                      const void* __restrict__ distance,
                      unsigned short* __restrict__ eH, unsigned short* __restrict__ eL,
                      const int* __restrict__ flagp) {
  const int f = *flagp;
  const int vtx = blockIdx.x;
  const int bb = vtx >> 10, i = vtx & 1023;
  const int t = threadIdx.x;
  const int id = idxO[bb * 1024 + i];
  const int cy = id / 100, cx = id % 100;
  const float nvx = ((float)cx - 50.0f + 0.5f) / 100.0f;
  const float nvy = ((float)cy - 25.0f + 0.5f) / 50.0f;
  const int c = t;
  float val;
  if (c == 0) val = nvx;
  else if (c == 1) val = nvy;
  else if (c < 42) {
    int d = c - 2, fq = d >> 2, r = d & 3;
    float freq = (float)(1 << fq);
    float ang = ((r == 0 || r == 2) ? nvx : nvy) * freq;
    val = (r < 2) ? sinf(ang) : cosf(ang);
  } else if (c == 42) {
    val = valsO[bb * 1024 + i];
  } else if (c < 235) {
    int d = c - 43, cls = d >> 6, ii = (d >> 3) & 7, jj = d & 7;
    val = ldin(distance,
               (((long long)bb * 3 + cls) * 400 + (cy * 8 + ii)) * 800 + (cx * 8 + jj), f);
  } else {
    val = 0.f;
  }
  unsigned short h_ = f2bf(val);
  eH[(long long)vtx * 256 + c] = h_;
  eL[(long long)vtx * 256 + c] = f2bf(val - bf2f(h_));
}

// ----------------------------------------------- plane MFMA GEMM (NT, bf16x3)
template <int MODE, bool SPLIT, bool W3F>
__global__ __launch_bounds__(256) void gemm_pl(
    const unsigned short* __restrict__ Ah, const unsigned short* __restrict__ Al,
    const unsigned short* __restrict__ A2h, const unsigned short* __restrict__ A2l,
    int lda, const unsigned short* __restrict__ WHp,
    const unsigned short* __restrict__ WLp, const void* __restrict__ bias,
    const void* __restrict__ bn, float* __restrict__ CoutF,
    unsigned short* __restrict__ CoutH, unsigned short* __restrict__ CoutL,
    int ldc, int N, int K, float scale,
    long long aBatch, long long wBatch, long long cBatch,
    long long wOff, long long bOff, long long bnOff,
    const int* __restrict__ flagp) {
  const int rf = *flagp;
  const bool w3 = W3F || (rf != 0);
  const unsigned short* Ahp = Ah + (long long)blockIdx.z * aBatch;
  const unsigned short* Alp = Al + (long long)blockIdx.z * aBatch;
  CoutF += (long long)blockIdx.z * cBatch;
  const long long wb = wOff + (long long)blockIdx.z * wBatch;
  __shared__ unsigned short AH[2112], AL[2112], BH[2112], BL[2112];
  const int t = threadIdx.x;
  const int m0 = blockIdx.y * 64, n0 = blockIdx.x * 64;
  const int w = t >> 6, lane = t & 63, quad = lane >> 4, l15 = lane & 15;
  ushort4 rah[2], ral[2], rbh[2], rbl[2];
  auto loadT = [&](int k0) {
#pragma unroll
    for (int i = 0; i < 2; i++) {
      int id = t + (i << 8);
      int m = id >> 3, k4 = (id & 7) << 2;
      int kc = k0 + k4;
      const unsigned short* ph = Ahp;
      const unsigned short* pl = Alp;
      int kk = kc;
      if (SPLIT && kc >= 256) { ph = A2h; pl = A2l; kk = kc - 256; }
      long long ai = (long long)(m0 + m) * lda + kk;
      rah[i] = *(const ushort4*)&ph[ai];
      ral[i] = *(const ushort4*)&pl[ai];
      long long wi = wb + (long long)(n0 + m) * K + kc;
      rbh[i] = *(const ushort4*)&WHp[wi];
      rbl[i] = *(const ushort4*)&WLp[wi];
    }
  };
  auto storeT = [&]() {
#pragma unroll
    for (int i = 0; i < 2; i++) {
      int id = t + (i << 8);
      int m = id >> 3, k4 = (id & 7) << 2;
      int q = k4 >> 3, j0 = k4 & 7;
      int li = (q * 66 + m) * 8 + j0;  // pad 64->66: q-stride shifts 8 banks
      *(ushort4*)&AH[li] = rah[i];
      *(ushort4*)&AL[li] = ral[i];
      *(ushort4*)&BH[li] = rbh[i];
      *(ushort4*)&BL[li] = rbl[i];
    }
  };
  f32x4 acc[4];
#pragma unroll
  for (int c = 0; c < 4; c++) acc[c] = (f32x4){0.f, 0.f, 0.f, 0.f};
  loadT(0);
  const int mr = w * 16 + l15;
  for (int k0 = 0; k0 < K; k0 += 32) {
    storeT();
    __syncthreads();
    if (k0 + 32 < K) loadT(k0 + 32);
    short8 fa = *(const short8*)&AH[(quad * 66 + mr) * 8];
    short8 fal = *(const short8*)&AL[(quad * 66 + mr) * 8];
#pragma unroll
    for (int cb = 0; cb < 4; cb++) {
      int nr = cb * 16 + l15;
      short8 fb = *(const short8*)&BH[(quad * 66 + nr) * 8];
      acc[cb] = __builtin_amdgcn_mfma_f32_16x16x32_bf16(fa, fb, acc[cb], 0, 0, 0);
      acc[cb] = __builtin_amdgcn_mfma_f32_16x16x32_bf16(fal, fb, acc[cb], 0, 0, 0);
      if (w3) {
        short8 fbl = *(const short8*)&BL[(quad * 66 + nr) * 8];
        acc[cb] = __builtin_amdgcn_mfma_f32_16x16x32_bf16(fa, fbl, acc[cb], 0, 0, 0);
      }
    }
    __syncthreads();
  }
#pragma unroll
  for (int cb = 0; cb < 4; cb++) {
    const int n = n0 + cb * 16 + l15;
    float bv = 0.f, g = 0.f, bt = 0.f, mu = 0.f, vr = 0.f;
    if (MODE != 4) {
      long long bidx;
      if (MODE == 3) {
        int c = n & 255;
        bidx = bOff + (long long)(n >> 8) * 256 + (c & 63) * 4 + (c >> 6);
      } else {
        bidx = bOff + n;
      }
      bv = ldin(bias, bidx, rf);
    }
    if (MODE == 1) {
      g = ldin(bn, bnOff + n, rf);
      bt = ldin(bn, bnOff + N + n, rf);
      mu = ldin(bn, bnOff + 2 * N + n, rf);
      vr = ldin(bn, bnOff + 3 * N + n, rf);
    }
#pragma unroll
    for (int r = 0; r < 4; r++) {
      const int m = m0 + w * 16 + quad * 4 + r;
      float v = acc[cb][r];
      if (MODE == 4) v *= scale;
      else v += bv;
      if (MODE == 1) {
        v = g * (v - mu) / sqrtf(vr + 1e-5f) + bt;
        v = fmaxf(v, 0.f);
      }
      if (MODE == 2) v += CoutF[(long long)m * ldc + n];
      if (MODE == 2 || MODE == 3 || MODE == 4 || MODE == 5)
        CoutF[(long long)m * ldc + n] = v;
      if (MODE == 0 || MODE == 1 || MODE == 2 || MODE == 5) {
        unsigned short hh = f2bf(v);
        CoutH[(long long)m * ldc + n] = hh;
        CoutL[(long long)m * ldc + n] = f2bf(v - bf2f(hh));
      }
    }
  }
}

// ------------------------------------------------ per-(b,h) mean of V rows
__global__ __launch_bounds__(256) void k_meanv(const float* __restrict__ QKV,
                                               float* __restrict__ meanV) {
  const int bh = blockIdx.x;  // 0..15
  const int t = threadIdx.x;
  const int c4 = t >> 6, d = t & 63;
  __shared__ float part[4][64];
  const float* Vb = QKV + (long long)(bh >> 2) * 1024 * 768 + 512 + (bh & 3) * 64;
  float s = 0.f;
  for (int r = c4 * 256; r < (c4 + 1) * 256; r++) s += Vb[(long long)r * 768 + d];
  part[c4][d] = s;
  __syncthreads();
  if (c4 == 0)
    meanV[bh * 64 + d] =
        (part[0][d] + part[1][d] + part[2][d] + part[3][d]) * (1.f / 1024.f);
}

// -------------------------------------------------- flash-style attention
// q-tile 32, 128 threads, 512 blocks (2/CU). Thread (q2,j8) owns 2q x 8k.
// P stays in registers; PV sources P via __shfl from owning lane (no Pst).
__global__ __launch_bounds__(128) void k_attn(
    const float* __restrict__ QKV, const float* __restrict__ maskf,
    const int* __restrict__ nvp, const float* __restrict__ meanV,
    unsigned short* __restrict__ msgH, unsigned short* __restrict__ msgL) {
  const int qt = blockIdx.x, h = blockIdx.y, bb = blockIdx.z;
  const int t = threadIdx.x;
  const int q2 = t >> 3, j8 = t & 7;  // q2 0..15, j8 0..7
  const int lane = t & 63;
  __shared__ float Qst[64][36];
  __shared__ float Kst[64][68];
  __shared__ float Vs[64][72];
  __shared__ float qm[32], km[64];
  const float* Qb = QKV + (long long)bb * 1024 * 768 + h * 64;
  const float* Kb = Qb + 256;
  const float* Vb = Qb + 512;
  const int q0 = qt * 32;
  const int nv = nvp[bb];
  const int nt = (nv + 63) >> 6;
  float mi[2] = {-INFINITY, -INFINITY};
  float li[2] = {0.f, 0.f};
  float o[2][8] = {};
  if (q0 < nv) {
#pragma unroll
    for (int i = 0; i < 4; i++) {
      int id = t + i * 128;
      int q = id >> 4, d4 = (id & 15) << 2;
      float4 qv = *(const float4*)&Qb[(long long)(q0 + q) * 768 + d4];
      Qst[d4][q] = qv.x; Qst[d4 + 1][q] = qv.y;
      Qst[d4 + 2][q] = qv.z; Qst[d4 + 3][q] = qv.w;
    }
    if (t < 32) qm[t] = maskf[bb * 1024 + q0 + t];
    __syncthreads();
    const float qmr[2] = {qm[2 * q2], qm[2 * q2 + 1]};
    for (int kt = 0; kt < nt; kt++) {
      const int k0 = kt * 64;
      __syncthreads();  // prev PV done before restage
#pragma unroll
      for (int i = 0; i < 8; i++) {
        int id = t + i * 128;
        int n = id >> 4, d4 = (id & 15) << 2;
        float4 kv = *(const float4*)&Kb[(long long)(k0 + n) * 768 + d4];
        Kst[d4][n] = kv.x; Kst[d4 + 1][n] = kv.y;
        Kst[d4 + 2][n] = kv.z; Kst[d4 + 3][n] = kv.w;
        float4 vvv = *(const float4*)&Vb[(long long)(k0 + n) * 768 + d4];
        *(float4*)&Vs[n][d4] = vvv;
      }
      if (t < 64) km[t] = maskf[bb * 1024 + k0 + t];
      __syncthreads();
      float kmr[8];
#pragma unroll
      for (int kk = 0; kk < 8; kk++) kmr[kk] = km[8 * j8 + kk];
      float s[2][8] = {};
      for (int d = 0; d < 64; d++) {
        float2 qv = *(const float2*)&Qst[d][2 * q2];
        float4 ka = *(const float4*)&Kst[d][8 * j8];
        float4 kb = *(const float4*)&Kst[d][8 * j8 + 4];
        s[0][0] = fmaf(qv.x, ka.x, s[0][0]); s[0][1] = fmaf(qv.x, ka.y, s[0][1]);
        s[0][2] = fmaf(qv.x, ka.z, s[0][2]); s[0][3] = fmaf(qv.x, ka.w, s[0][3]);
        s[0][4] = fmaf(qv.x, kb.x, s[0][4]); s[0][5] = fmaf(qv.x, kb.y, s[0][5]);
        s[0][6] = fmaf(qv.x, kb.z, s[0][6]); s[0][7] = fmaf(qv.x, kb.w, s[0][7]);
        s[1][0] = fmaf(qv.y, ka.x, s[1][0]); s[1][1] = fmaf(qv.y, ka.y, s[1][1]);
        s[1][2] = fmaf(qv.y, ka.z, s[1][2]); s[1][3] = fmaf(qv.y, ka.w, s[1][3]);
        s[1][4] = fmaf(qv.y, kb.x, s[1][4]); s[1][5] = fmaf(qv.y, kb.y, s[1][5]);
        s[1][6] = fmaf(qv.y, kb.z, s[1][6]); s[1][7] = fmaf(qv.y, kb.w, s[1][7]);
      }
#pragma unroll
      for (int qq = 0; qq < 2; qq++) {
        float rm = -INFINITY;
#pragma unroll
        for (int kk = 0; kk < 8; kk++) {
          float val = (qmr[qq] * kmr[kk] == 0.f) ? -1e9f : s[qq][kk] * 0.125f;
          s[qq][kk] = val;
          rm = fmaxf(rm, val);
        }
        rm = fmaxf(rm, __shfl_xor(rm, 1));
        rm = fmaxf(rm, __shfl_xor(rm, 2));
        rm = fmaxf(rm, __shfl_xor(rm, 4));
        float nm = fmaxf(mi[qq], rm);
        float al = __expf(mi[qq] - nm);
        mi[qq] = nm;
        float sum = 0.f;
#pragma unroll
        for (int kk = 0; kk < 8; kk++) {
          float p = __expf(s[qq][kk] - nm);
          s[qq][kk] = p;
          sum += p;
        }
        sum += __shfl_xor(sum, 1);
        sum += __shfl_xor(sum, 2);
        sum += __shfl_xor(sum, 4);
        li[qq] = li[qq] * al + sum;
#pragma unroll
        for (int dd = 0; dd < 8; dd++) o[qq][dd] *= al;
      }
      // PV: P sourced from owning lane via shuffle (m = 8*jj + kk owned by
      // lane (lane&0x38)|jj, register s[qq][kk]).
#pragma unroll
      for (int jj = 0; jj < 8; jj++) {
        const int src = (lane & 0x38) | jj;
#pragma unroll
        for (int kk = 0; kk < 8; kk++) {
          const int m = 8 * jj + kk;
          float p0 = __shfl(s[0][kk], src, 64);
          float p1 = __shfl(s[1][kk], src, 64);
          float4 va = *(const float4*)&Vs[m][8 * j8];
          float4 vb = *(const float4*)&Vs[m][8 * j8 + 4];
          o[0][0] = fmaf(p0, va.x, o[0][0]); o[0][1] = fmaf(p0, va.y, o[0][1]);
          o[0][2] = fmaf(p0, va.z, o[0][2]); o[0][3] = fmaf(p0, va.w, o[0][3]);
          o[0][4] = fmaf(p0, vb.x, o[0][4]); o[0][5] = fmaf(p0, vb.y, o[0][5]);
          o[0][6] = fmaf(p0, vb.z, o[0][6]); o[0][7] = fmaf(p0, vb.w, o[0][7]);
          o[1][0] = fmaf(p1, va.x, o[1][0]); o[1][1] = fmaf(p1, va.y, o[1][1]);
          o[1][2] = fmaf(p1, va.z, o[1][2]); o[1][3] = fmaf(p1, va.w, o[1][3]);
          o[1][4] = fmaf(p1, vb.x, o[1][4]); o[1][5] = fmaf(p1, vb.y, o[1][5]);
          o[1][6] = fmaf(p1, vb.z, o[1][6]); o[1][7] = fmaf(p1, vb.w, o[1][7]);
        }
      }
    }
  }
#pragma unroll
  for (int qq = 0; qq < 2; qq++) {
    const int q = q0 + 2 * q2 + qq;
    const long long idx = ((long long)bb * 1024 + q) * 256 + h * 64 + 8 * j8;
    const float inv = (q < nv) ? (1.f / li[qq]) : 0.f;
#pragma unroll
    for (int dd = 0; dd < 8; dd++) {
      float val = (q < nv) ? o[qq][dd] * inv
                           : meanV[((bb * 4 + h) << 6) + 8 * j8 + dd];
      unsigned short hh = f2bf(val);
      msgH[idx + dd] = hh;
      msgL[idx + dd] = f2bf(val - bf2f(hh));
    }
  }
}

// ------------------------------------------------------------- border (col 1024)
__global__ void k_border(float* __restrict__ C, const void* __restrict__ alpha,
                         const int* __restrict__ flagp) {
  const int f = *flagp;
  int g = blockIdx.x * 256 + threadIdx.x;
  if (g >= 4096) return;
  float a = ldin(alpha, 0, f);
  int bb = g >> 10, r = g & 1023;
  C[(long long)bb * 1050625 + (long long)r * 1025 + 1024] = a;
}

// -------------------------------------------------------------- Sinkhorn
// 4 groups x 32 blocks x 512 thr; expC = exp(C-rowmax) in LDS (wave-private
// rows, no barriers at all). u/v entries are 8B atoms (float val | uint seq);
// readers poll seq on the data itself -> one visibility hop per half.
// Lockstep: every wave reads ALL entries of S before writing D, so no entry
// can be overwritten before all readers of the previous half finished.
__global__ __launch_bounds__(512) void k_sinkhorn(
    const float* __restrict__ C, const void* __restrict__ alphap,
    unsigned long long* u2, unsigned long long* v2, void* __restrict__ outv,
    const int* __restrict__ flagp) {
  extern __shared__ float expC[];  // 32*1025
  const int f = *flagp;
  const int bb = blockIdx.x >> 5;
  const int blk = blockIdx.x & 31;
  const int t = threadIdx.x;
  const int wid = t >> 6, lane = t & 63;
  const int r0g = blk << 5;   // block's 32 rows
  const int rw = wid << 2;    // wave's 4 local rows
  const float alpha = ldin(alphap, 0, f);
  const float* Cb = C + (long long)bb * 1050625;
  unsigned long long* ub = u2 + bb * 1025;
  unsigned long long* vb = v2 + bb * 1025;
  const float NORM = -7.624619086159398f;  // -log(2048)
  const float BIN = -0.6931471805599453f;  // log(1024)-log(2048)
  const bool isAlpha = (blk == 0 && wid == 0);
  float mcr[4];
#pragma unroll
  for (int j = 0; j < 4; j++) {  // wave-private rows: no __syncthreads needed
    const float* src = Cb + (long long)(r0g + rw + j) * 1025;
    float* drow = expC + (rw + j) * 1025;
    float vals[17];
    float mx = -INFINITY;
#pragma unroll
    for (int i = 0; i < 17; i++) {
      int col = (i << 6) + lane;
      float x = (col <= 1024) ? src[col] : -INFINITY;
      vals[i] = x;
      mx = fmaxf(mx, x);
    }
#pragma unroll
    for (int o = 32; o; o >>= 1) mx = fmaxf(mx, __shfl_xor(mx, o, 64));
    mcr[j] = mx;
#pragma unroll
    for (int i = 0; i < 17; i++) {
      int col = (i << 6) + lane;
      if (col <= 1024) drow[col] = __expf(vals[i] - mx);
    }
  }
  float lastU[4] = {0, 0, 0, 0};
  float lastAU = 0.f;
  for (int half = 0; half < 200; half++) {
    const unsigned long long* S = (half & 1) ? ub : vb;
    unsigned long long* D = (half & 1) ? vb : ub;
    const unsigned hseq = (unsigned)half;
    float svr[17];
#pragma unroll
    for (int i = 0; i < 17; i++) {
      int col = (i << 6) + lane;
      if (col <= 1024) {
        unsigned long long p;
        for (;;) {
          p = __hip_atomic_load(S + col, __ATOMIC_RELAXED, __HIP_MEMORY_SCOPE_AGENT);
          if ((unsigned)(p >> 32) >= hseq) break;
          __builtin_amdgcn_s_sleep(1);
        }
        svr[i] = __expf(__uint_as_float((unsigned)p));
      } else {
        svr[i] = 0.f;
      }
    }
    const unsigned long long wseq = (unsigned long long)(unsigned)(half + 1) << 32;
    float outs[4];
#pragma unroll
    for (int j = 0; j < 4; j++) {
      const float* cr = expC + (rw + j) * 1025;
      float s = 0.f;
#pragma unroll
      for (int i = 0; i < 17; i++) {
        int col = (i << 6) + lane;
        int cc = (col <= 1024) ? col : 0;  // svr=0 masks tail
        s = fmaf(cr[cc], svr[i], s);
      }
#pragma unroll
      for (int o = 32; o; o >>= 1) s += __shfl_xor(s, o, 64);
      outs[j] = NORM - (mcr[j] + __logf(s));
    }
    if ((half & 1) == 0) {
#pragma unroll
      for (int j = 0; j < 4; j++) lastU[j] = outs[j];
    }
    if (lane == 0) {
#pragma unroll
      for (int j = 0; j < 4; j++)
        __hip_atomic_store(D + r0g + rw + j, wseq | __float_as_uint(outs[j]),
                           __ATOMIC_RELAXED, __HIP_MEMORY_SCOPE_AGENT);
    }
    if (isAlpha) {  // alpha row: LSE = alpha + log(sum exp(sv))
      float s = 0.f;
#pragma unroll
      for (int i = 0; i < 17; i++) s += svr[i];
#pragma unroll
      for (int o = 32; o; o >>= 1) s += __shfl_xor(s, o, 64);
      float nval = BIN - (alpha + __logf(s));
      if ((half & 1) == 0) lastAU = nval;
      if (lane == 0)
        __hip_atomic_store(D + 1024, wseq | __float_as_uint(nval),
                           __ATOMIC_RELAXED, __HIP_MEMORY_SCOPE_AGENT);
    }
  }
  // epilogue: final v (vb, seq 200); final u for own rows = lastU.
  float svf[17];
#pragma unroll
  for (int i = 0; i < 17; i++) {
    int col = (i << 6) + lane;
    if (col <= 1024) {
      unsigned long long p;
      for (;;) {
        p = __hip_atomic_load(vb + col, __ATOMIC_RELAXED, __HIP_MEMORY_SCOPE_AGENT);
        if ((unsigned)(p >> 32) >= 200u) break;
        __builtin_amdgcn_s_sleep(1);
      }
      svf[i] = __uint_as_float((unsigned)p);
    } else {
      svf[i] = 0.f;
    }
  }
  const long long base = (long long)bb * 1050625;
#pragma unroll
  for (int j = 0; j < 4; j++) {
    const int row = r0g + rw + j;
    const float* src = Cb + (long long)row * 1025;
    const float un = lastU[j];
#pragma unroll
    for (int i = 0; i < 17; i++) {
      int col = (i << 6) + lane;
      if (col <= 1024) {
        float val = src[col] + un + svf[i] - NORM;
        if (f) ((float*)outv)[base + (long long)row * 1025 + col] = val;
        else ((bf16*)outv)[base + (long long)row * 1025 + col] = __float2bfloat16(val);
      }
    }
  }
  if (isAlpha) {
    const float un = lastAU;
#pragma unroll
    for (int i = 0; i < 17; i++) {
      int col = (i << 6) + lane;
      if (col <= 1024) {
        float val = alpha + un + svf[i] - NORM;
        if (f) ((float*)outv)[base + (long long)1024 * 1025 + col] = val;
        else ((bf16*)outv)[base + (long long)1024 * 1025 + col] = __float2bfloat16(val);
      }
    }
  }
}

// ================================================================== launch
extern "C" void kernel_launch(void* const* d_in, const int* in_sizes, int n_in,
                              void* d_out, int out_size, void* d_ws, size_t ws_size,
                              hipStream_t stream) {
  const void* scores = d_in[0];
  const void* distance = d_in[1];
  const void* enc_W0 = d_in[2];
  const void* enc_b0 = d_in[3];
  const void* enc_bn = d_in[4];
  const void* enc_W1 = d_in[5];
  const void* enc_b1 = d_in[6];
  const void* gnn_Wqkv = d_in[7];
  const void* gnn_bqkv = d_in[8];
  const void* gnn_Wm = d_in[9];
  const void* gnn_bm = d_in[10];
  const void* gnn_W1 = d_in[11];
  const void* gnn_b1 = d_in[12];
  const void* gnn_bn = d_in[13];
  const void* gnn_W2 = d_in[14];
  const void* gnn_b2 = d_in[15];
  const void* final_W = d_in[16];
  const void* final_b = d_in[17];
  const void* alpha = d_in[18];
  (void)in_sizes; (void)n_in; (void)out_size; (void)ws_size;

  char* ws = (char*)d_ws;
  size_t off = 0;
  auto alloc = [&](size_t bytes) -> void* {
    void* p = ws + off;
    off += (bytes + 255) & ~(size_t)255;
    return p;
  };
  typedef unsigned short ush;
  int* flag = (int*)alloc(256);
  int* nvA = (int*)alloc(256);
  int* idxO = (int*)alloc(4096 * 4);
  float* valsO = (float*)alloc(4096 * 4);
  float* maskO = (float*)alloc(4096 * 4);
  ush* WH = (ush*)alloc((size_t)2818048 * 2);
  ush* WL = (ush*)alloc((size_t)2818048 * 2);
  ush* embH = (ush*)alloc((size_t)1048576 * 2);
  ush* embL = (ush*)alloc((size_t)1048576 * 2);
  ush* T0H = (ush*)alloc((size_t)1048576 * 2);
  ush* T0L = (ush*)alloc((size_t)1048576 * 2);
  ush* XH = (ush*)alloc((size_t)1048576 * 2);
  ush* XL = (ush*)alloc((size_t)1048576 * 2);
  float* Xf = (float*)alloc((size_t)1048576 * 4);
  float* QKVf = (float*)alloc((size_t)3145728 * 4);
  float* meanV = (float*)alloc(1024 * 4);
  ush* msgH = (ush*)alloc((size_t)1048576 * 2);
  ush* msgL = (ush*)alloc((size_t)1048576 * 2);
  ush* M2H = (ush*)alloc((size_t)1048576 * 2);
  ush* M2L = (ush*)alloc((size_t)1048576 * 2);
  ush* Y1H = (ush*)alloc((size_t)2097152 * 2);
  ush* Y1L = (ush*)alloc((size_t)2097152 * 2);
  ush* MDH = (ush*)alloc((size_t)1048576 * 2);
  ush* MDL = (ush*)alloc((size_t)1048576 * 2);
  float* Cpl = (float*)alloc((size_t)4 * 1050625 * 4);
  unsigned long long* u2 = (unsigned long long*)alloc((size_t)4 * 1025 * 8);
  unsigned long long* v2 = (unsigned long long*)alloc((size_t)4 * 1025 * 8);

  hipMemsetAsync(u2, 0, (size_t)4 * 1025 * 8, stream);
  hipMemsetAsync(v2, 0, (size_t)4 * 1025 * 8, stream);

  static bool attrSet = false;
  if (!attrSet) {
    hipFuncSetAttribute(reinterpret_cast<const void*>(&k_sinkhorn),
                        hipFuncAttributeMaxDynamicSharedMemorySize, 131200);
    hipFuncSetAttribute(reinterpret_cast<const void*>(&k_front),
                        hipFuncAttributeMaxDynamicSharedMemorySize, 120000);
    attrSet = true;
  }

  const dim3 b256(256);
  k_front<<<4, 1024, 120000, stream>>>(scores, distance, flag, idxO, valsO,
                                       maskO, nvA);
  k_prep<<<11008, b256, 0, stream>>>(enc_W0, enc_W1, gnn_Wqkv, gnn_Wm, gnn_W1,
                                     gnn_W2, final_W, WH, WL, flag);
  k_emb<<<4096, b256, 0, stream>>>(idxO, valsO, distance, embH, embL, flag);

  // encoder
  gemm_pl<1, false, false><<<dim3(4, 64, 1), b256, 0, stream>>>(
      embH, embL, nullptr, nullptr, 256, WH + 0, WL + 0, enc_b0, enc_bn,
      nullptr, T0H, T0L, 256, 256, 256, 1.f, 0, 0, 0, 0, 0, 0, flag);
  gemm_pl<5, false, false><<<dim3(4, 64, 1), b256, 0, stream>>>(
      T0H, T0L, nullptr, nullptr, 256, WH + 65536, WL + 65536, enc_b1, nullptr,
      Xf, XH, XL, 256, 256, 256, 1.f, 0, 0, 0, 0, 0, 0, flag);

  for (int l = 0; l < 4; l++) {
    gemm_pl<3, false, false><<<dim3(12, 64, 1), b256, 0, stream>>>(
        XH, XL, nullptr, nullptr, 256, WH + 131072, WL + 131072, gnn_bqkv,
        nullptr, QKVf, nullptr, nullptr, 768, 768, 256, 1.f, 0, 0, 0,
        (long long)l * 196608, (long long)l * 768, 0, flag);
    k_meanv<<<16, b256, 0, stream>>>(QKVf, meanV);
    k_attn<<<dim3(32, 4, 4), dim3(128), 0, stream>>>(QKVf, maskO, nvA, meanV,
                                                     msgH, msgL);
    gemm_pl<0, false, false><<<dim3(4, 64, 1), b256, 0, stream>>>(
        msgH, msgL, nullptr, nullptr, 256, WH + 917504, WL + 917504, gnn_bm,
        nullptr, nullptr, M2H, M2L, 256, 256, 256, 1.f, 0, 0, 0,
        (long long)l * 65536, (long long)l * 256, 0, flag);
    gemm_pl<1, true, false><<<dim3(8, 64, 1), b256, 0, stream>>>(
        XH, XL, M2H, M2L, 256, WH + 1179648, WL + 1179648, gnn_b1, gnn_bn,
        nullptr, Y1H, Y1L, 512, 512, 512, 1.f, 0, 0, 0,
        (long long)l * 262144, (long long)l * 512, (long long)l * 2048, flag);
    gemm_pl<2, false, false><<<dim3(4, 64, 1), b256, 0, stream>>>(
        Y1H, Y1L, nullptr, nullptr, 512, WH + 2228224, WL + 2228224, gnn_b2,
        nullptr, Xf, XH, XL, 256, 256, 512, 1.f, 0, 0, 0,
        (long long)l * 131072, (long long)l * 256, 0, flag);
  }
  gemm_pl<0, false, false><<<dim3(4, 64, 1), b256, 0, stream>>>(
      XH, XL, nullptr, nullptr, 256, WH + 2752512, WL + 2752512, final_b,
      nullptr, nullptr, MDH, MDL, 256, 256, 256, 1.f, 0, 0, 0, 0, 0, 0, flag);
  gemm_pl<4, false, true><<<dim3(16, 16, 4), b256, 0, stream>>>(
      MDH, MDL, nullptr, nullptr, 256, MDH, MDL, nullptr, nullptr, Cpl, nullptr,
      nullptr, 1025, 1024, 256, 0.0625f, 262144, 262144, 1050625, 0, 0, 0, flag);
  k_border<<<16, b256, 0, stream>>>(Cpl, alpha, flag);
  k_sinkhorn<<<128, 512, 131200, stream>>>(Cpl, alpha, u2, v2, d_out, flag);
}